// Round 2
// baseline (97.336 us; speedup 1.0000x reference)
//
#include <hip/hip_runtime.h>

// NT-Xent positive-pair loss:
//   cos_k = dot(z_i[k], z_j[k]) / max(||z_i[k]|| * ||z_j[k]||, EPS)
//   loss  = sum_k (cos_k / T)^2 * 2 / N^2,  N = 2B
// B = 16384, D = 512, T = 0.5, EPS = 1e-8.
//
// Best-measured structure (R3, 91.1us; re-anchored R1 this session, 91.6us).
// Measured dead ends: cooperative grid.sync +101us (R2); last-block finalize
// w/ __threadfence+counter +17us (R4); barrier-free wave partials neutral (R5).
// Timed window: ~41.5us ws re-poison fill (measured 6.5 TB/s = 81% peak,
// top-5 counters R1) + ~21us input restore + our ~13us (compulsory 67MB read
// ~10.5us at the 6.5 TB/s achieved ceiling + ~2us finalize + gaps).
//
// R2 probe: __builtin_nontemporal_load on the read-once input streams ->
// avoid L2/L3 allocation churn for dead lines. nt is a replacement hint
// (not a bypass) on CDNA, so neutral worst-case, small win if allocation
// overhead was costing BW.
//
// Kernel 1: 2048 blocks x 256 thr = 32 waves/CU (max occupancy). 32 lanes
// per row, 2 rows/wave, 8 rows/block -> exactly 16384 rows, one pass.
// Kernel 2: one 64-lane wave reduces 2048 partials, writes scaled scalar.

constexpr int   D_DIM  = 512;
constexpr float EPS    = 1e-8f;
constexpr float INV_TEMP = 2.0f;                          // 1 / 0.5
constexpr float SCALE    = 2.0f / (32768.0f * 32768.0f);  // 2 / N^2

using f32x4 = __attribute__((ext_vector_type(4))) float;

__global__ __launch_bounds__(256) void ntxent_partial_kernel(
    const float* __restrict__ zi,
    const float* __restrict__ zj,
    float* __restrict__ partials)
{
    const int lane        = threadIdx.x & 63;
    const int wave_in_blk = threadIdx.x >> 6;
    const int g    = lane & 31;   // lane within 32-lane row-group
    const int grp  = lane >> 5;   // 0..1: which row this group handles
    const int wave = blockIdx.x * 4 + wave_in_blk;   // 0..8191
    const int row  = wave * 2 + grp;                 // 0..16383, one pass

    const f32x4* a4 = (const f32x4*)(zi + (size_t)row * D_DIM);
    const f32x4* b4 = (const f32x4*)(zj + (size_t)row * D_DIM);

    float dot = 0.0f, na = 0.0f, nb = 0.0f;
    // 512 floats / 32 lanes = 4 float4 per lane; each load instruction covers
    // two contiguous 512B spans in two adjacent rows (full cache lines).
    // Nontemporal: data is read exactly once per timed iteration.
    #pragma unroll
    for (int k = 0; k < 4; ++k) {
        f32x4 a = __builtin_nontemporal_load(a4 + g + 32 * k);
        f32x4 b = __builtin_nontemporal_load(b4 + g + 32 * k);
        dot += a.x * b.x + a.y * b.y + a.z * b.z + a.w * b.w;
        na  += a.x * a.x + a.y * a.y + a.z * a.z + a.w * a.w;
        nb  += b.x * b.x + b.y * b.y + b.z * b.z + b.w * b.w;
    }

    // Reduce across the 32 lanes of the row-group (5 xor steps).
    #pragma unroll
    for (int m = 16; m >= 1; m >>= 1) {
        dot += __shfl_xor(dot, m, 64);
        na  += __shfl_xor(na,  m, 64);
        nb  += __shfl_xor(nb,  m, 64);
    }

    float acc = 0.0f;
    if (g == 0) {   // lanes 0 and 32 hold one row's result each
        float norm_prod = sqrtf(na) * sqrtf(nb);
        float cosv = dot / fmaxf(norm_prod, EPS);
        float pos  = cosv * INV_TEMP;
        acc = pos * pos;
    }
    acc += __shfl_xor(acc, 32, 64);   // combine the wave's two rows

    __shared__ float s[4];
    if (lane == 0) s[wave_in_blk] = acc;
    __syncthreads();
    if (threadIdx.x == 0)
        partials[blockIdx.x] = (s[0] + s[1]) + (s[2] + s[3]);
}

__global__ __launch_bounds__(64) void ntxent_finalize_kernel(
    const float* __restrict__ partials,
    float* __restrict__ out)
{
    // 2048 partials = 512 float4; 64 lanes x 8 float4 each, coalesced.
    const f32x4* p4 = (const f32x4*)partials;
    const int lane = threadIdx.x;
    float v = 0.0f;
    #pragma unroll
    for (int k = 0; k < 8; ++k) {
        f32x4 p = p4[lane + 64 * k];
        v += (p.x + p.y) + (p.z + p.w);
    }
    #pragma unroll
    for (int m = 32; m >= 1; m >>= 1)
        v += __shfl_xor(v, m, 64);
    if (lane == 0)
        out[0] = v * SCALE;
}

extern "C" void kernel_launch(void* const* d_in, const int* in_sizes, int n_in,
                              void* d_out, int out_size, void* d_ws, size_t ws_size,
                              hipStream_t stream)
{
    const float* zi = (const float*)d_in[0];
    const float* zj = (const float*)d_in[1];
    float* partials = (float*)d_ws;   // 2048 floats = 8 KiB of scratch
    float* out = (float*)d_out;

    ntxent_partial_kernel<<<2048, 256, 0, stream>>>(zi, zj, partials);
    ntxent_finalize_kernel<<<1, 64, 0, stream>>>(partials, out);
}

// Round 4
// 91.007 us; speedup vs baseline: 1.0696x; 1.0696x over previous
//
#include <hip/hip_runtime.h>

// NT-Xent positive-pair loss:
//   cos_k = dot(z_i[k], z_j[k]) / max(||z_i[k]|| * ||z_j[k]||, EPS)
//   loss  = sum_k (cos_k / T)^2 * 2 / N^2,  N = 2B
// B = 16384, D = 512, T = 0.5, EPS = 1e-8.
//
// Best-measured structure (prev session R3 91.1us; this session R1 91.6us).
// Measured dead ends: cooperative grid.sync +101us; last-block finalize w/
// __threadfence+counter +17us; barrier-free wave partials neutral;
// nontemporal input loads +2.5us beyond global drift (R2 this session).
//
// R2 lesson: the harness's input-restore (re-write of the 67MB inputs) runs
// AFTER the 268MB ws poison and right before our dispatch -> the input rows
// are L2/L3-warm when we read them. Plain loads exploit the hit path; NT
// loads discard it and regress. So the timed window is: ~41.5us poison fill
// (measured 6.5 TB/s = 81% peak) + ~21us input restore + our ~13us
// (67MB cache-warm read + ~2us finalize + dispatch gaps). Remaining levers
// are all <2us = below session noise (+/-3us container clock drift).
//
// Kernel 1: 2048 blocks x 256 thr = 32 waves/CU (max occupancy). 32 lanes
// per row, 2 rows/wave, 8 rows/block -> exactly 16384 rows, one pass.
// Kernel 2: one 64-lane wave reduces 2048 partials, writes scaled scalar.

constexpr int   D_DIM  = 512;
constexpr float EPS    = 1e-8f;
constexpr float INV_TEMP = 2.0f;                          // 1 / 0.5
constexpr float SCALE    = 2.0f / (32768.0f * 32768.0f);  // 2 / N^2

__global__ __launch_bounds__(256) void ntxent_partial_kernel(
    const float* __restrict__ zi,
    const float* __restrict__ zj,
    float* __restrict__ partials)
{
    const int lane        = threadIdx.x & 63;
    const int wave_in_blk = threadIdx.x >> 6;
    const int g    = lane & 31;   // lane within 32-lane row-group
    const int grp  = lane >> 5;   // 0..1: which row this group handles
    const int wave = blockIdx.x * 4 + wave_in_blk;   // 0..8191
    const int row  = wave * 2 + grp;                 // 0..16383, one pass

    const float4* a4 = (const float4*)(zi + (size_t)row * D_DIM);
    const float4* b4 = (const float4*)(zj + (size_t)row * D_DIM);

    float dot = 0.0f, na = 0.0f, nb = 0.0f;
    // 512 floats / 32 lanes = 4 float4 per lane; each load instruction covers
    // two contiguous 512B spans in two adjacent rows (full cache lines).
    #pragma unroll
    for (int k = 0; k < 4; ++k) {
        float4 a = a4[g + 32 * k];
        float4 b = b4[g + 32 * k];
        dot += a.x * b.x + a.y * b.y + a.z * b.z + a.w * b.w;
        na  += a.x * a.x + a.y * a.y + a.z * a.z + a.w * a.w;
        nb  += b.x * b.x + b.y * b.y + b.z * b.z + b.w * b.w;
    }

    // Reduce across the 32 lanes of the row-group (5 xor steps).
    #pragma unroll
    for (int m = 16; m >= 1; m >>= 1) {
        dot += __shfl_xor(dot, m, 64);
        na  += __shfl_xor(na,  m, 64);
        nb  += __shfl_xor(nb,  m, 64);
    }

    float acc = 0.0f;
    if (g == 0) {   // lanes 0 and 32 hold one row's result each
        float norm_prod = sqrtf(na) * sqrtf(nb);
        float cosv = dot / fmaxf(norm_prod, EPS);
        float pos  = cosv * INV_TEMP;
        acc = pos * pos;
    }
    acc += __shfl_xor(acc, 32, 64);   // combine the wave's two rows

    __shared__ float s[4];
    if (lane == 0) s[wave_in_blk] = acc;
    __syncthreads();
    if (threadIdx.x == 0)
        partials[blockIdx.x] = (s[0] + s[1]) + (s[2] + s[3]);
}

__global__ __launch_bounds__(64) void ntxent_finalize_kernel(
    const float* __restrict__ partials,
    float* __restrict__ out)
{
    // 2048 partials = 512 float4; 64 lanes x 8 float4 each, coalesced.
    const float4* p4 = (const float4*)partials;
    const int lane = threadIdx.x;
    float v = 0.0f;
    #pragma unroll
    for (int k = 0; k < 8; ++k) {
        float4 p = p4[lane + 64 * k];
        v += (p.x + p.y) + (p.z + p.w);
    }
    #pragma unroll
    for (int m = 32; m >= 1; m >>= 1)
        v += __shfl_xor(v, m, 64);
    if (lane == 0)
        out[0] = v * SCALE;
}

extern "C" void kernel_launch(void* const* d_in, const int* in_sizes, int n_in,
                              void* d_out, int out_size, void* d_ws, size_t ws_size,
                              hipStream_t stream)
{
    const float* zi = (const float*)d_in[0];
    const float* zj = (const float*)d_in[1];
    float* partials = (float*)d_ws;   // 2048 floats = 8 KiB of scratch
    float* out = (float*)d_out;

    ntxent_partial_kernel<<<2048, 256, 0, stream>>>(zi, zj, partials);
    ntxent_finalize_kernel<<<1, 64, 0, stream>>>(partials, out);
}